// Round 6
// baseline (647.876 us; speedup 1.0000x reference)
//
#include <hip/hip_runtime.h>

#define KVOL 8
#define NIN 40000
#define NOUT 150000
#define C 128
#define EPSV 1e-5f
#define NPAIR (KVOL * NOUT)
#define GM ((NOUT + 63) / 64)          // 2344 (parts sizing)
#define GM2 ((NOUT + 127) / 128)       // 1172 (128-row MFMA tiles)
#define GUP (NIN / 64)                 // 625
#define GATH ((NOUT + 63) / 64)        // 2344
#define NBUCK ((NOUT + 255) / 256)     // 586 coarse buckets (256 rows each)
#define BCAP 4096                      // slots per bucket (mean 2048, sigma ~45)

typedef __attribute__((ext_vector_type(8))) __bf16 bf16x8;
typedef __attribute__((ext_vector_type(4))) float f32x4;
typedef __attribute__((ext_vector_type(8))) unsigned short us8;

__device__ __forceinline__ unsigned short fbf(float f) {
    unsigned u = __float_as_uint(f);
    u += 0x7fffu + ((u >> 16) & 1u);
    return (unsigned short)(u >> 16);
}
__device__ __forceinline__ float bff(unsigned short s) {
    return __uint_as_float(((unsigned)s) << 16);
}

// =============== weight prep: WT[b][n][k] = bf16(W_b[k][n]), b in {Wup0..7, W1a, W1b, W2} =======
__global__ __launch_bounds__(256) void k_prep_w(
    const float* __restrict__ Wup, const float* __restrict__ W1, const float* __restrict__ W2,
    unsigned short* __restrict__ WT)
{
    int i = blockIdx.x * 256 + threadIdx.x;
    if (i < 11 * 16384) {
        int b = i >> 14, r = i & 16383;
        int k = r >> 7, n = r & 127;
        const float* src = (b < 8) ? (Wup + (size_t)b * 16384)
                         : (b < 10) ? (W1 + (size_t)(b - 8) * 16384) : W2;
        WT[(size_t)b * 16384 + n * 128 + k] = fbf(src[k * 128 + n]);
    }
}

// =============== up GEMM: Y[k] = x @ Wup[k] (bf16 out); A staged once, loop k ===============
// A frag: m = lane&15, k = kk*32 + (lane>>4)*8 + i (same map both operands -> permutation cancels)
// C/D frag: col = lane&15, row = (lane>>4)*4 + reg
__global__ __launch_bounds__(256) void k_up(
    const float* __restrict__ x, const unsigned short* __restrict__ WT,
    unsigned short* __restrict__ Y)
{
    __shared__ __align__(16) unsigned short Alds[64][136];
    __shared__ __align__(16) unsigned short Wlds[128][136];
    const int t = threadIdx.x;
    const int wave = t >> 6, lane = t & 63;
    const int l15 = lane & 15, lhi = lane >> 4;
    const int R = blockIdx.x * 64;
    const float4* A4 = (const float4*)x;
    #pragma unroll
    for (int j = 0; j < 8; ++j) {
        int idx = t + j * 256;
        int row = idx >> 5, c4 = idx & 31;
        int grow = R + row;
        float4 v = make_float4(0.f, 0.f, 0.f, 0.f);
        if (grow < NIN) v = A4[(size_t)grow * 32 + c4];
        ushort4 o;
        o.x = fbf(v.x); o.y = fbf(v.y); o.z = fbf(v.z); o.w = fbf(v.w);
        *(ushort4*)&Alds[row][c4 * 4] = o;
    }
    __syncthreads();
    bf16x8 af[4];
    #pragma unroll
    for (int kk = 0; kk < 4; ++kk)
        af[kk] = *(const bf16x8*)&Alds[wave * 16 + l15][kk * 32 + lhi * 8];
    for (int k = 0; k < KVOL; ++k) {
        __syncthreads();
        const us8* Wsrc = (const us8*)(WT + (size_t)k * C * C);
        #pragma unroll
        for (int j = 0; j < 8; ++j) {
            int slot = t + j * 256;
            int n = slot >> 4, koff = (slot & 15) * 8;
            *(us8*)&Wlds[n][koff] = Wsrc[slot];
        }
        __syncthreads();
        f32x4 acc[8];
        #pragma unroll
        for (int n = 0; n < 8; ++n) acc[n] = (f32x4){0.f, 0.f, 0.f, 0.f};
        #pragma unroll
        for (int n = 0; n < 8; ++n) {
            #pragma unroll
            for (int kk = 0; kk < 4; ++kk) {
                bf16x8 bfr = *(const bf16x8*)&Wlds[n * 16 + l15][kk * 32 + lhi * 8];
                acc[n] = __builtin_amdgcn_mfma_f32_16x16x32_bf16(af[kk], bfr, acc[n], 0, 0, 0);
            }
        }
        unsigned short* Yk = Y + (size_t)k * NIN * C;
        #pragma unroll
        for (int n = 0; n < 8; ++n) {
            const int col = n * 16 + l15;
            #pragma unroll
            for (int r = 0; r < 4; ++r) {
                int row = R + wave * 16 + lhi * 4 + r;
                if (row < NIN) Yk[(size_t)row * C + col] = fbf(acc[n][r]);
            }
        }
    }
}

// =============== main MFMA GEMM (128x128 tile, 512 thr): out = bf16( sum_ph A_ph @ W_ph + b ) ====
// A0 always bf16 (+ optional fused BN-ReLU); A1 (PHASES==2) always fp32, prefetched in regs.
template<int PHASES, bool BNIN, bool STATS>
__global__ __launch_bounds__(512) void k_mfma(
    const void* __restrict__ A0v, const void* __restrict__ A1v,
    const unsigned short* __restrict__ WT,
    const float* __restrict__ bias,
    unsigned short* __restrict__ outp, int M,
    const float* __restrict__ bn_stats, const float* __restrict__ bn_g, const float* __restrict__ bn_b,
    float* __restrict__ parts)
{
    __shared__ __align__(16) unsigned short Alds[128][136];
    __shared__ __align__(16) unsigned short Wlds[128][136];
    __shared__ float sscale[C], sshift[C];
    const int t = threadIdx.x;
    const int wave = t >> 6, lane = t & 63;
    const int l15 = lane & 15, lhi = lane >> 4;
    const int R = blockIdx.x * 128;

    if (BNIN) {
        if (t < C) {
            float m = bn_stats[t] * (1.0f / NOUT);
            float var = bn_stats[C + t] * (1.0f / NOUT) - m * m;
            float sc = bn_g[t] * rsqrtf(var + EPSV);
            sscale[t] = sc;
            sshift[t] = fmaf(-m, sc, bn_b[t]);
        }
        __syncthreads();
    }

    f32x4 acc[8];
    #pragma unroll
    for (int n = 0; n < 8; ++n) acc[n] = (f32x4){0.f, 0.f, 0.f, 0.f};

    // ---- stage phase 0: W (bf16 linear copy) + A0 (bf16, optional BN+ReLU) ----
    {
        const us8* Wsrc = (const us8*)WT;
        #pragma unroll
        for (int j = 0; j < 4; ++j) {
            int slot = t + j * 512;
            *(us8*)&Wlds[slot >> 4][(slot & 15) * 8] = Wsrc[slot];
        }
        const us8* A8 = (const us8*)A0v;
        #pragma unroll
        for (int j = 0; j < 4; ++j) {
            int slot = t + j * 512;
            int row = slot >> 4, s15 = slot & 15, koff = s15 * 8;
            int grow = R + row;
            us8 v = (us8){0, 0, 0, 0, 0, 0, 0, 0};
            if (grow < M) v = A8[(size_t)grow * 16 + s15];
            if (BNIN) {
                us8 w;
                #pragma unroll
                for (int i = 0; i < 8; ++i) {
                    float f = fmaxf(fmaf(bff(v[i]), sscale[koff + i], sshift[koff + i]), 0.f);
                    w[i] = fbf(f);
                }
                v = w;
            }
            *(us8*)&Alds[row][koff] = v;
        }
    }
    __syncthreads();

    if constexpr (PHASES == 2) {
        // prefetch phase 1 (W1b + fp32 A1) into registers while phase 0 computes
        us8 wreg[4];
        float4 areg[8];
        {
            const us8* Wsrc1 = (const us8*)(WT + C * C);
            #pragma unroll
            for (int j = 0; j < 4; ++j) wreg[j] = Wsrc1[t + j * 512];
            const float4* A41 = (const float4*)A1v;
            #pragma unroll
            for (int j = 0; j < 8; ++j) {
                int slot = t + j * 512;
                int row = slot >> 5, c4 = slot & 31;
                int grow = R + row;
                float4 v = make_float4(0.f, 0.f, 0.f, 0.f);
                if (grow < M) v = A41[(size_t)grow * 32 + c4];
                areg[j] = v;
            }
        }
        // compute phase 0
        {
            bf16x8 af[4];
            #pragma unroll
            for (int kk = 0; kk < 4; ++kk)
                af[kk] = *(const bf16x8*)&Alds[wave * 16 + l15][kk * 32 + lhi * 8];
            #pragma unroll
            for (int n = 0; n < 8; ++n) {
                #pragma unroll
                for (int kk = 0; kk < 4; ++kk) {
                    bf16x8 bfr = *(const bf16x8*)&Wlds[n * 16 + l15][kk * 32 + lhi * 8];
                    acc[n] = __builtin_amdgcn_mfma_f32_16x16x32_bf16(af[kk], bfr, acc[n], 0, 0, 0);
                }
            }
        }
        __syncthreads();
        // write phase 1 staging from registers
        #pragma unroll
        for (int j = 0; j < 4; ++j) {
            int slot = t + j * 512;
            *(us8*)&Wlds[slot >> 4][(slot & 15) * 8] = wreg[j];
        }
        #pragma unroll
        for (int j = 0; j < 8; ++j) {
            int slot = t + j * 512;
            int row = slot >> 5, c4 = slot & 31;
            float4 v = areg[j];
            ushort4 o;
            o.x = fbf(v.x); o.y = fbf(v.y); o.z = fbf(v.z); o.w = fbf(v.w);
            *(ushort4*)&Alds[row][c4 * 4] = o;
        }
        __syncthreads();
    }
    // compute last phase
    {
        bf16x8 af[4];
        #pragma unroll
        for (int kk = 0; kk < 4; ++kk)
            af[kk] = *(const bf16x8*)&Alds[wave * 16 + l15][kk * 32 + lhi * 8];
        #pragma unroll
        for (int n = 0; n < 8; ++n) {
            #pragma unroll
            for (int kk = 0; kk < 4; ++kk) {
                bf16x8 bfr = *(const bf16x8*)&Wlds[n * 16 + l15][kk * 32 + lhi * 8];
                acc[n] = __builtin_amdgcn_mfma_f32_16x16x32_bf16(af[kk], bfr, acc[n], 0, 0, 0);
            }
        }
    }
    __syncthreads();   // Alds/Wlds dead; safe to reuse Alds for stats

    float* sbS = (float*)&Alds[0][0];       // [8][128]
    float* sbQ = sbS + 1024;                // [8][128]
    #pragma unroll
    for (int n = 0; n < 8; ++n) {
        const int col = n * 16 + l15;
        float bv = bias[col];
        float s = 0.f, q = 0.f;
        #pragma unroll
        for (int r = 0; r < 4; ++r) {
            int row = R + wave * 16 + lhi * 4 + r;
            if (row < M) {
                float v = acc[n][r] + bv;
                outp[(size_t)row * C + col] = fbf(v);
                if (STATS) { s += v; q = fmaf(v, v, q); }
            }
        }
        if (STATS) {
            s += __shfl_xor(s, 16); s += __shfl_xor(s, 32);
            q += __shfl_xor(q, 16); q += __shfl_xor(q, 32);
            if (lane < 16) {
                sbS[wave * 128 + col] = s;
                sbQ[wave * 128 + col] = q;
            }
        }
    }
    if (STATS) {
        __syncthreads();
        if (t < 128) {
            float S = 0.f;
            #pragma unroll
            for (int w = 0; w < 8; ++w) S += sbS[w * 128 + t];
            parts[(size_t)blockIdx.x * 256 + t] = S;
        } else if (t < 256) {
            int cc = t - 128;
            float Q = 0.f;
            #pragma unroll
            for (int w = 0; w < 8; ++w) Q += sbQ[w * 128 + cc];
            parts[(size_t)blockIdx.x * 256 + t] = Q;
        }
    }
}

// =============== stats partial reduction ===============
__global__ __launch_bounds__(256) void k_reduce(const float* __restrict__ parts, int nb,
                                                float* __restrict__ stats)
{
    const int t = threadIdx.x;
    float s0 = 0.f, s1 = 0.f, s2 = 0.f, s3 = 0.f;
    for (int b = blockIdx.x * 4; b < nb; b += gridDim.x * 4) {
        if (b < nb)     s0 += parts[(size_t)b * 256 + t];
        if (b + 1 < nb) s1 += parts[(size_t)(b + 1) * 256 + t];
        if (b + 2 < nb) s2 += parts[(size_t)(b + 2) * 256 + t];
        if (b + 3 < nb) s3 += parts[(size_t)(b + 3) * 256 + t];
    }
    atomicAdd(&stats[t], (s0 + s1) + (s2 + s3));
}

// =============== bucket append: pairs -> coarse buckets (o>>8), packed (o&255)<<24 | entry ======
__global__ __launch_bounds__(256) void k_bucket(
    const int* __restrict__ pout, const int* __restrict__ pin,
    int* __restrict__ bcnt, unsigned int* __restrict__ bbuf)
{
    const int p = blockIdx.x * 256 + threadIdx.x;
    const int k = blockIdx.y;
    if (p < NOUT) {
        int o = pout[k * NOUT + p];
        unsigned e = (unsigned)(k * NIN + pin[k * NOUT + p]);   // < 2^19
        int b = o >> 8;
        int pos = atomicAdd(&bcnt[b], 1);
        if (pos < BCAP) bbuf[(size_t)b * BCAP + pos] = ((unsigned)(o & 255) << 24) | e;
    }
}

// =============== per-bucket counting sort: LDS hist+scan, starts/len out, in-place sorted =======
__global__ __launch_bounds__(256) void k_binsort(
    const int* __restrict__ bcnt, unsigned int* __restrict__ bbuf,
    int* __restrict__ starts, int* __restrict__ lenp)
{
    __shared__ unsigned int pr[BCAP];
    __shared__ int cnt[256];
    __shared__ int ofs[256];
    __shared__ int sd[256];
    const int t = threadIdx.x;
    const int b = blockIdx.x;
    const int n = min(bcnt[b], BCAP);
    unsigned int* gbase = bbuf + (size_t)b * BCAP;
    for (int j = t; j < n; j += 256) pr[j] = gbase[j];
    cnt[t] = 0;
    __syncthreads();
    for (int j = t; j < n; j += 256) atomicAdd(&cnt[pr[j] >> 24], 1);
    __syncthreads();
    // exclusive scan of cnt
    sd[t] = cnt[t];
    __syncthreads();
    for (int off = 1; off < 256; off <<= 1) {
        int a = sd[t];
        int bb = (t >= off) ? sd[t - off] : 0;
        __syncthreads();
        sd[t] = a + bb;
        __syncthreads();
    }
    ofs[t] = sd[t] - cnt[t];
    const int o = b * 256 + t;
    if (o < NOUT) {
        starts[o] = b * BCAP + ofs[t];
        lenp[o] = cnt[t];
    }
    __syncthreads();
    // scatter sorted entries back in place (reads already staged in LDS)
    for (int j = t; j < n; j += 256) {
        unsigned p = pr[j];
        int pos = atomicAdd(&ofs[p >> 24], 1);
        gbase[pos] = p & 0xFFFFFFu;
    }
}

// =============== gather-reduce: up_raw[o] (bf16) = sum Y[entry]; BN0 stats partials ===============
__global__ __launch_bounds__(256) void k_gather(
    const us8* __restrict__ Y8, const int* __restrict__ starts, const int* __restrict__ lenp,
    const unsigned int* __restrict__ entries,
    us8* __restrict__ up8, float* __restrict__ parts)
{
    __shared__ float sS[16][16][8];
    __shared__ float sQ[16][16][8];
    const int t = threadIdx.x;
    const int rl = t >> 4, c8 = t & 15;
    float s[8], q[8];
    #pragma unroll
    for (int i = 0; i < 8; ++i) { s[i] = 0.f; q[i] = 0.f; }
    const int base = blockIdx.x * 64;
    #pragma unroll
    for (int it = 0; it < 4; ++it) {
        int o = base + it * 16 + rl;
        if (o < NOUT) {
            int j0 = starts[o], j1 = j0 + lenp[o];
            float a[8];
            #pragma unroll
            for (int i = 0; i < 8; ++i) a[i] = 0.f;
            int j = j0;
            for (; j + 1 < j1; j += 2) {
                unsigned e0 = entries[j], e1 = entries[j + 1];
                us8 u0 = Y8[(size_t)e0 * 16 + c8];
                us8 u1 = Y8[(size_t)e1 * 16 + c8];
                #pragma unroll
                for (int i = 0; i < 8; ++i) a[i] += bff(u0[i]) + bff(u1[i]);
            }
            if (j < j1) {
                unsigned e0 = entries[j];
                us8 u0 = Y8[(size_t)e0 * 16 + c8];
                #pragma unroll
                for (int i = 0; i < 8; ++i) a[i] += bff(u0[i]);
            }
            us8 o8;
            #pragma unroll
            for (int i = 0; i < 8; ++i) {
                o8[i] = fbf(a[i]);
                s[i] += a[i];
                q[i] = fmaf(a[i], a[i], q[i]);
            }
            up8[(size_t)o * 16 + c8] = o8;
        }
    }
    #pragma unroll
    for (int i = 0; i < 8; ++i) { sS[rl][c8][i] = s[i]; sQ[rl][c8][i] = q[i]; }
    __syncthreads();
    if (t < 128) {
        const int cc = t >> 3, ii = t & 7;
        float S = 0.f, Q = 0.f;
        #pragma unroll
        for (int r = 0; r < 16; ++r) { S += sS[r][cc][ii]; Q += sQ[r][cc][ii]; }
        parts[(size_t)blockIdx.x * 256 + t] = S;
        parts[(size_t)blockIdx.x * 256 + 128 + t] = Q;
    }
}

// =============== final: out = relu(bn2(h2)) + relu(bn0(up_raw)), fp32 out ===============
__global__ __launch_bounds__(256) void k_final(
    const us8* __restrict__ h2, const us8* __restrict__ upr, float* __restrict__ out,
    const float* __restrict__ stats2, const float* __restrict__ g2, const float* __restrict__ be2,
    const float* __restrict__ stats0, const float* __restrict__ g0, const float* __restrict__ b0)
{
    __shared__ float sc2[C], sh2[C], sc0[C], sh0[C];
    const int t = threadIdx.x;
    if (t < C) {
        float m2 = stats2[t] * (1.0f / NOUT);
        float v2 = stats2[C + t] * (1.0f / NOUT) - m2 * m2;
        float c2 = g2[t] * rsqrtf(v2 + EPSV);
        sc2[t] = c2; sh2[t] = fmaf(-m2, c2, be2[t]);
        float m0 = stats0[t] * (1.0f / NOUT);
        float v0 = stats0[C + t] * (1.0f / NOUT) - m0 * m0;
        float c0 = g0[t] * rsqrtf(v0 + EPSV);
        sc0[t] = c0; sh0[t] = fmaf(-m0, c0, b0[t]);
    }
    __syncthreads();
    const int idx0 = blockIdx.x * 256 + t;
    const int c8 = idx0 & 15;
    float l2s[8], l2h[8], l0s[8], l0h[8];
    #pragma unroll
    for (int i = 0; i < 8; ++i) {
        l2s[i] = sc2[c8 * 8 + i]; l2h[i] = sh2[c8 * 8 + i];
        l0s[i] = sc0[c8 * 8 + i]; l0h[i] = sh0[c8 * 8 + i];
    }
    const int total = NOUT * 16;
    for (int idx = idx0; idx < total; idx += gridDim.x * 256) {
        us8 h = h2[idx];
        us8 u = upr[idx];
        float o[8];
        #pragma unroll
        for (int i = 0; i < 8; ++i) {
            o[i] = fmaxf(fmaf(bff(h[i]), l2s[i], l2h[i]), 0.f)
                 + fmaxf(fmaf(bff(u[i]), l0s[i], l0h[i]), 0.f);
        }
        float4* dst = (float4*)&out[(size_t)idx * 8];
        dst[0] = make_float4(o[0], o[1], o[2], o[3]);
        dst[1] = make_float4(o[4], o[5], o[6], o[7]);
    }
}

extern "C" void kernel_launch(void* const* d_in, const int* in_sizes, int n_in,
                              void* d_out, int out_size, void* d_ws, size_t ws_size,
                              hipStream_t stream)
{
    const float* x    = (const float*)d_in[0];
    const float* skip = (const float*)d_in[1];
    const int*   pin  = (const int*)d_in[2];
    const int*   pout = (const int*)d_in[3];
    const float* Wup  = (const float*)d_in[4];
    const float* g0   = (const float*)d_in[5];
    const float* b0   = (const float*)d_in[6];
    const float* W1   = (const float*)d_in[7];
    const float* b1   = (const float*)d_in[8];
    const float* g1   = (const float*)d_in[9];
    const float* be1  = (const float*)d_in[10];
    const float* W2   = (const float*)d_in[11];
    const float* b2   = (const float*)d_in[12];
    const float* g2   = (const float*)d_in[13];
    const float* be2  = (const float*)d_in[14];
    float* outp = (float*)d_out;

    // ws layout: Y (82MB) reused by h1/h2 after gather; up_raw separate
    char* base = (char*)d_ws;
    unsigned short* Y      = (unsigned short*)base;               // 81,920,000 B
    unsigned short* h1     = (unsigned short*)base;               // alias (Y dead)
    unsigned short* h2     = (unsigned short*)(base + 40960000);  // alias (no overlap with h1)
    unsigned short* up_raw = (unsigned short*)(base + 81920000);  // 38,400,000 B
    char* p = base + 81920000 + 38400000;
    unsigned short* WT = (unsigned short*)p; p += (size_t)11 * 16384 * 2;
    unsigned int* bbuf = (unsigned int*)p;  p += (size_t)NBUCK * BCAP * 4;   // 9.6 MB
    int* bcnt      = (int*)p; p += (size_t)((NBUCK + 63) / 64) * 64 * 4;
    int* starts    = (int*)p; p += (size_t)(NOUT + 64) * 4;
    int* lenp      = (int*)p; p += (size_t)(NOUT + 64) * 4;
    float* parts0  = (float*)p; p += (size_t)GATH * 256 * 4;
    float* parts1  = (float*)p; p += (size_t)GM * 256 * 4;
    float* parts2  = (float*)p; p += (size_t)GM * 256 * 4;
    float* stats   = (float*)p; p += 3 * 256 * 4;   // stats0 | stats1 | stats2

    hipMemsetAsync(bcnt, 0, (size_t)NBUCK * 4, stream);
    hipMemsetAsync(stats, 0, 3 * 256 * 4, stream);

    // 0. weights -> bf16 transposed
    k_prep_w<<<(11 * 16384 + 255) / 256, 256, 0, stream>>>(Wup, W1, W2, WT);

    // 1. Y[k] = x @ Wup[k]
    k_up<<<GUP, 256, 0, stream>>>(x, WT, Y);

    // 2. CSR build via 2-level bucket sort (L2-resident write frontiers)
    k_bucket<<<dim3((NOUT + 255) / 256, KVOL), 256, 0, stream>>>(pout, pin, bcnt, bbuf);
    k_binsort<<<NBUCK, 256, 0, stream>>>(bcnt, bbuf, starts, lenp);

    // 3. gather-reduce -> up_raw bf16 + BN0 stats
    k_gather<<<GATH, 256, 0, stream>>>((const us8*)Y, starts, lenp, bbuf, (us8*)up_raw, parts0);
    k_reduce<<<16, 256, 0, stream>>>(parts0, GATH, stats);

    // 4. h1 = bf16( relu(bn0(up_raw)) @ W1[:128] + skip @ W1[128:] + b1 ) + BN1 stats
    k_mfma<2, true, true><<<GM2, 512, 0, stream>>>(
        up_raw, skip, WT + (size_t)8 * 16384, b1, h1, NOUT, stats, g0, b0, parts1);
    k_reduce<<<16, 256, 0, stream>>>(parts1, GM2, stats + 256);

    // 5. h2 = bf16( relu(bn1(h1)) @ W2 + b2 ) + BN2 stats
    k_mfma<1, true, true><<<GM2, 512, 0, stream>>>(
        h1, nullptr, WT + (size_t)10 * 16384, b2, h2, NOUT, stats + 256, g1, be1, parts2);
    k_reduce<<<16, 256, 0, stream>>>(parts2, GM2, stats + 512);

    // 6. out = relu(bn2(h2)) + relu(bn0(up_raw))
    k_final<<<1024, 256, 0, stream>>>((const us8*)h2, (const us8*)up_raw, outp,
        stats + 512, g2, be2, stats, g0, b0);
}

// Round 7
// 296.822 us; speedup vs baseline: 2.1827x; 2.1827x over previous
//
#include <hip/hip_runtime.h>

#define KVOL 8
#define NIN 40000
#define NOUT 150000
#define C 128
#define EPSV 1e-5f
#define NPAIR (KVOL * NOUT)
#define GM ((NOUT + 63) / 64)          // parts sizing
#define GM2 ((NOUT + 127) / 128)       // 1172 (128-row MFMA tiles)
#define GUP (NIN / 64)                 // 625
#define NBUCK ((NOUT + 255) / 256)     // 586 coarse buckets (256 rows each)
#define NSTR 8                         // bucket stripes (~1 per XCD)
#define SCAP 768                       // slots per stripe-bucket (mean 256, sigma ~16)
#define BCAP 4096                      // LDS staging per bucket (mean 2048, sigma ~45)
#define GBUCK ((NPAIR + 4095) / 4096)  // 293

typedef __attribute__((ext_vector_type(8))) __bf16 bf16x8;
typedef __attribute__((ext_vector_type(4))) float f32x4;
typedef __attribute__((ext_vector_type(8))) unsigned short us8;

__device__ __forceinline__ unsigned short fbf(float f) {
    unsigned u = __float_as_uint(f);
    u += 0x7fffu + ((u >> 16) & 1u);
    return (unsigned short)(u >> 16);
}
__device__ __forceinline__ float bff(unsigned short s) {
    return __uint_as_float(((unsigned)s) << 16);
}

// =============== weight prep: WT[b][n][k] = bf16(W_b[k][n]), b in {Wup0..7, W1a, W1b, W2} =======
__global__ __launch_bounds__(256) void k_prep_w(
    const float* __restrict__ Wup, const float* __restrict__ W1, const float* __restrict__ W2,
    unsigned short* __restrict__ WT)
{
    int i = blockIdx.x * 256 + threadIdx.x;
    if (i < 11 * 16384) {
        int b = i >> 14, r = i & 16383;
        int k = r >> 7, n = r & 127;
        const float* src = (b < 8) ? (Wup + (size_t)b * 16384)
                         : (b < 10) ? (W1 + (size_t)(b - 8) * 16384) : W2;
        WT[(size_t)b * 16384 + n * 128 + k] = fbf(src[k * 128 + n]);
    }
}

// =============== up GEMM: Y[k] = x @ Wup[k] (bf16 out); A staged once, loop k ===============
// A frag: m = lane&15, k = kk*32 + (lane>>4)*8 + i (same map both operands -> permutation cancels)
// C/D frag: col = lane&15, row = (lane>>4)*4 + reg
__global__ __launch_bounds__(256) void k_up(
    const float* __restrict__ x, const unsigned short* __restrict__ WT,
    unsigned short* __restrict__ Y)
{
    __shared__ __align__(16) unsigned short Alds[64][136];
    __shared__ __align__(16) unsigned short Wlds[128][136];
    const int t = threadIdx.x;
    const int wave = t >> 6, lane = t & 63;
    const int l15 = lane & 15, lhi = lane >> 4;
    const int R = blockIdx.x * 64;
    const float4* A4 = (const float4*)x;
    #pragma unroll
    for (int j = 0; j < 8; ++j) {
        int idx = t + j * 256;
        int row = idx >> 5, c4 = idx & 31;
        int grow = R + row;
        float4 v = make_float4(0.f, 0.f, 0.f, 0.f);
        if (grow < NIN) v = A4[(size_t)grow * 32 + c4];
        ushort4 o;
        o.x = fbf(v.x); o.y = fbf(v.y); o.z = fbf(v.z); o.w = fbf(v.w);
        *(ushort4*)&Alds[row][c4 * 4] = o;
    }
    __syncthreads();
    bf16x8 af[4];
    #pragma unroll
    for (int kk = 0; kk < 4; ++kk)
        af[kk] = *(const bf16x8*)&Alds[wave * 16 + l15][kk * 32 + lhi * 8];
    for (int k = 0; k < KVOL; ++k) {
        __syncthreads();
        const us8* Wsrc = (const us8*)(WT + (size_t)k * C * C);
        #pragma unroll
        for (int j = 0; j < 8; ++j) {
            int slot = t + j * 256;
            int n = slot >> 4, koff = (slot & 15) * 8;
            *(us8*)&Wlds[n][koff] = Wsrc[slot];
        }
        __syncthreads();
        f32x4 acc[8];
        #pragma unroll
        for (int n = 0; n < 8; ++n) acc[n] = (f32x4){0.f, 0.f, 0.f, 0.f};
        #pragma unroll
        for (int n = 0; n < 8; ++n) {
            #pragma unroll
            for (int kk = 0; kk < 4; ++kk) {
                bf16x8 bfr = *(const bf16x8*)&Wlds[n * 16 + l15][kk * 32 + lhi * 8];
                acc[n] = __builtin_amdgcn_mfma_f32_16x16x32_bf16(af[kk], bfr, acc[n], 0, 0, 0);
            }
        }
        unsigned short* Yk = Y + (size_t)k * NIN * C;
        #pragma unroll
        for (int n = 0; n < 8; ++n) {
            const int col = n * 16 + l15;
            #pragma unroll
            for (int r = 0; r < 4; ++r) {
                int row = R + wave * 16 + lhi * 4 + r;
                if (row < NIN) Yk[(size_t)row * C + col] = fbf(acc[n][r]);
            }
        }
    }
}

// =============== main MFMA GEMM (128x128 tile, 512 thr): out = bf16( sum_ph A_ph @ W_ph + b ) ====
template<int PHASES, bool BNIN, bool STATS>
__global__ __launch_bounds__(512) void k_mfma(
    const void* __restrict__ A0v, const void* __restrict__ A1v,
    const unsigned short* __restrict__ WT,
    const float* __restrict__ bias,
    unsigned short* __restrict__ outp, int M,
    const float* __restrict__ bn_stats, const float* __restrict__ bn_g, const float* __restrict__ bn_b,
    float* __restrict__ parts)
{
    __shared__ __align__(16) unsigned short Alds[128][136];
    __shared__ __align__(16) unsigned short Wlds[128][136];
    __shared__ float sscale[C], sshift[C];
    const int t = threadIdx.x;
    const int wave = t >> 6, lane = t & 63;
    const int l15 = lane & 15, lhi = lane >> 4;
    const int R = blockIdx.x * 128;

    if (BNIN) {
        if (t < C) {
            float m = bn_stats[t] * (1.0f / NOUT);
            float var = bn_stats[C + t] * (1.0f / NOUT) - m * m;
            float sc = bn_g[t] * rsqrtf(var + EPSV);
            sscale[t] = sc;
            sshift[t] = fmaf(-m, sc, bn_b[t]);
        }
        __syncthreads();
    }

    f32x4 acc[8];
    #pragma unroll
    for (int n = 0; n < 8; ++n) acc[n] = (f32x4){0.f, 0.f, 0.f, 0.f};

    {
        const us8* Wsrc = (const us8*)WT;
        #pragma unroll
        for (int j = 0; j < 4; ++j) {
            int slot = t + j * 512;
            *(us8*)&Wlds[slot >> 4][(slot & 15) * 8] = Wsrc[slot];
        }
        const us8* A8 = (const us8*)A0v;
        #pragma unroll
        for (int j = 0; j < 4; ++j) {
            int slot = t + j * 512;
            int row = slot >> 4, s15 = slot & 15, koff = s15 * 8;
            int grow = R + row;
            us8 v = (us8){0, 0, 0, 0, 0, 0, 0, 0};
            if (grow < M) v = A8[(size_t)grow * 16 + s15];
            if (BNIN) {
                us8 w;
                #pragma unroll
                for (int i = 0; i < 8; ++i) {
                    float f = fmaxf(fmaf(bff(v[i]), sscale[koff + i], sshift[koff + i]), 0.f);
                    w[i] = fbf(f);
                }
                v = w;
            }
            *(us8*)&Alds[row][koff] = v;
        }
    }
    __syncthreads();

    if constexpr (PHASES == 2) {
        us8 wreg[4];
        float4 areg[8];
        {
            const us8* Wsrc1 = (const us8*)(WT + C * C);
            #pragma unroll
            for (int j = 0; j < 4; ++j) wreg[j] = Wsrc1[t + j * 512];
            const float4* A41 = (const float4*)A1v;
            #pragma unroll
            for (int j = 0; j < 8; ++j) {
                int slot = t + j * 512;
                int row = slot >> 5, c4 = slot & 31;
                int grow = R + row;
                float4 v = make_float4(0.f, 0.f, 0.f, 0.f);
                if (grow < M) v = A41[(size_t)grow * 32 + c4];
                areg[j] = v;
            }
        }
        {
            bf16x8 af[4];
            #pragma unroll
            for (int kk = 0; kk < 4; ++kk)
                af[kk] = *(const bf16x8*)&Alds[wave * 16 + l15][kk * 32 + lhi * 8];
            #pragma unroll
            for (int n = 0; n < 8; ++n) {
                #pragma unroll
                for (int kk = 0; kk < 4; ++kk) {
                    bf16x8 bfr = *(const bf16x8*)&Wlds[n * 16 + l15][kk * 32 + lhi * 8];
                    acc[n] = __builtin_amdgcn_mfma_f32_16x16x32_bf16(af[kk], bfr, acc[n], 0, 0, 0);
                }
            }
        }
        __syncthreads();
        #pragma unroll
        for (int j = 0; j < 4; ++j) {
            int slot = t + j * 512;
            *(us8*)&Wlds[slot >> 4][(slot & 15) * 8] = wreg[j];
        }
        #pragma unroll
        for (int j = 0; j < 8; ++j) {
            int slot = t + j * 512;
            int row = slot >> 5, c4 = slot & 31;
            float4 v = areg[j];
            ushort4 o;
            o.x = fbf(v.x); o.y = fbf(v.y); o.z = fbf(v.z); o.w = fbf(v.w);
            *(ushort4*)&Alds[row][c4 * 4] = o;
        }
        __syncthreads();
    }
    {
        bf16x8 af[4];
        #pragma unroll
        for (int kk = 0; kk < 4; ++kk)
            af[kk] = *(const bf16x8*)&Alds[wave * 16 + l15][kk * 32 + lhi * 8];
        #pragma unroll
        for (int n = 0; n < 8; ++n) {
            #pragma unroll
            for (int kk = 0; kk < 4; ++kk) {
                bf16x8 bfr = *(const bf16x8*)&Wlds[n * 16 + l15][kk * 32 + lhi * 8];
                acc[n] = __builtin_amdgcn_mfma_f32_16x16x32_bf16(af[kk], bfr, acc[n], 0, 0, 0);
            }
        }
    }
    __syncthreads();   // Alds/Wlds dead; reuse Alds for stats

    float* sbS = (float*)&Alds[0][0];       // [8][128]
    float* sbQ = sbS + 1024;                // [8][128]
    #pragma unroll
    for (int n = 0; n < 8; ++n) {
        const int col = n * 16 + l15;
        float bv = bias[col];
        float s = 0.f, q = 0.f;
        #pragma unroll
        for (int r = 0; r < 4; ++r) {
            int row = R + wave * 16 + lhi * 4 + r;
            if (row < M) {
                float v = acc[n][r] + bv;
                outp[(size_t)row * C + col] = fbf(v);
                if (STATS) { s += v; q = fmaf(v, v, q); }
            }
        }
        if (STATS) {
            s += __shfl_xor(s, 16); s += __shfl_xor(s, 32);
            q += __shfl_xor(q, 16); q += __shfl_xor(q, 32);
            if (lane < 16) {
                sbS[wave * 128 + col] = s;
                sbQ[wave * 128 + col] = q;
            }
        }
    }
    if (STATS) {
        __syncthreads();
        if (t < 128) {
            float S = 0.f;
            #pragma unroll
            for (int w = 0; w < 8; ++w) S += sbS[w * 128 + t];
            parts[(size_t)blockIdx.x * 256 + t] = S;
        } else if (t < 256) {
            int cc = t - 128;
            float Q = 0.f;
            #pragma unroll
            for (int w = 0; w < 8; ++w) Q += sbQ[w * 128 + cc];
            parts[(size_t)blockIdx.x * 256 + t] = Q;
        }
    }
}

// =============== stats partial reduction ===============
__global__ __launch_bounds__(256) void k_reduce(const float* __restrict__ parts, int nb,
                                                float* __restrict__ stats)
{
    const int t = threadIdx.x;
    float s0 = 0.f, s1 = 0.f, s2 = 0.f, s3 = 0.f;
    for (int b = blockIdx.x * 4; b < nb; b += gridDim.x * 4) {
        if (b < nb)     s0 += parts[(size_t)b * 256 + t];
        if (b + 1 < nb) s1 += parts[(size_t)(b + 1) * 256 + t];
        if (b + 2 < nb) s2 += parts[(size_t)(b + 2) * 256 + t];
        if (b + 3 < nb) s3 += parts[(size_t)(b + 3) * 256 + t];
    }
    atomicAdd(&stats[t], (s0 + s1) + (s2 + s3));
}

// =============== bucket append v2: LDS-aggregated counts, one atomic per (block,bucket) ========
// stripe = blockIdx.x & 7 (~XCD under round-robin dispatch) -> no cross-XCD cursor lines
__global__ __launch_bounds__(256) void k_bucket2(
    const int* __restrict__ pout, const int* __restrict__ pin,
    int* __restrict__ bcnt, unsigned int* __restrict__ bbuf)
{
    __shared__ int cnt[NBUCK];
    __shared__ int base[NBUCK];
    __shared__ int run[NBUCK];
    const int t = threadIdx.x;
    const int str = blockIdx.x & (NSTR - 1);
    const int i0 = blockIdx.x * 4096;
    for (int b = t; b < NBUCK; b += 256) { cnt[b] = 0; run[b] = 0; }
    __syncthreads();
    // pass 1: count buckets
    for (int j = t; j < 4096; j += 256) {
        int i = i0 + j;
        if (i < NPAIR) atomicAdd(&cnt[pout[i] >> 8], 1);
    }
    __syncthreads();
    // reserve ranges (one global atomic per non-empty bucket)
    for (int b = t; b < NBUCK; b += 256) {
        int c = cnt[b];
        base[b] = c ? atomicAdd(&bcnt[str * NBUCK + b], c) : 0;
    }
    __syncthreads();
    // pass 2: write packed entries into reserved runs
    for (int j = t; j < 4096; j += 256) {
        int i = i0 + j;
        if (i < NPAIR) {
            int o = pout[i];
            int k = i / NOUT;
            unsigned e = (unsigned)(k * NIN + pin[i]);          // < 2^19
            int b = o >> 8;
            int dst = base[b] + atomicAdd(&run[b], 1);
            if (dst < SCAP)
                bbuf[((size_t)str * NBUCK + b) * SCAP + dst] = ((unsigned)(o & 255) << 24) | e;
        }
    }
}

// =============== fused per-bucket counting sort + gather-reduce + BN0 stats ===============
// one block per bucket: load 8 stripe segments -> LDS, sort by row, gather Y, write up_raw
__global__ __launch_bounds__(256) void k_sortgather(
    const int* __restrict__ bcnt, const unsigned int* __restrict__ bbuf,
    const us8* __restrict__ Y8, us8* __restrict__ up8, float* __restrict__ parts)
{
    __shared__ unsigned int pr[BCAP];      // 16 KB; aliased by sS/sQ after sort
    __shared__ unsigned int srt[BCAP];     // 16 KB
    __shared__ int cnt[256], sd[256], ofs2[256];
    const int t = threadIdx.x;
    const int b = blockIdx.x;
    // load stripe segments contiguously into pr
    int segbase = 0;
    #pragma unroll
    for (int s = 0; s < NSTR; ++s) {
        int ns = min(bcnt[s * NBUCK + b], SCAP);
        const unsigned int* g = bbuf + ((size_t)s * NBUCK + b) * SCAP;
        for (int j = t; j < ns; j += 256) pr[segbase + j] = g[j];
        segbase += ns;
    }
    const int n = segbase;                 // total entries for this bucket (<= BCAP stat.)
    cnt[t] = 0;
    __syncthreads();
    for (int j = t; j < n; j += 256) atomicAdd(&cnt[pr[j] >> 24], 1);
    __syncthreads();
    sd[t] = cnt[t];
    __syncthreads();
    for (int off = 1; off < 256; off <<= 1) {
        int a = sd[t];
        int bb = (t >= off) ? sd[t - off] : 0;
        __syncthreads();
        sd[t] = a + bb;
        __syncthreads();
    }
    ofs2[t] = sd[t] - cnt[t];
    __syncthreads();
    for (int j = t; j < n; j += 256) {
        unsigned p = pr[j];
        int pos = atomicAdd(&ofs2[p >> 24], 1);
        srt[pos] = p & 0xFFFFFFu;
    }
    __syncthreads();                       // pr dead from here; alias stats onto it
    float* sS = (float*)pr;                // [16][16][8] = 8 KB
    float* sQ = sS + 2048;                 // [16][16][8] = 8 KB
    const int rl = t >> 4, c8 = t & 15;
    float s8[8], q8[8];
    #pragma unroll
    for (int i = 0; i < 8; ++i) { s8[i] = 0.f; q8[i] = 0.f; }
    #pragma unroll
    for (int it = 0; it < 16; ++it) {
        int r = it * 16 + rl;
        int o = b * 256 + r;
        if (o < NOUT) {
            int j1 = sd[r], j0 = j1 - cnt[r];
            float a[8];
            #pragma unroll
            for (int i = 0; i < 8; ++i) a[i] = 0.f;
            int j = j0;
            for (; j + 1 < j1; j += 2) {
                unsigned e0 = srt[j], e1 = srt[j + 1];
                us8 u0 = Y8[(size_t)e0 * 16 + c8];
                us8 u1 = Y8[(size_t)e1 * 16 + c8];
                #pragma unroll
                for (int i = 0; i < 8; ++i) a[i] += bff(u0[i]) + bff(u1[i]);
            }
            if (j < j1) {
                unsigned e0 = srt[j];
                us8 u0 = Y8[(size_t)e0 * 16 + c8];
                #pragma unroll
                for (int i = 0; i < 8; ++i) a[i] += bff(u0[i]);
            }
            us8 o8;
            #pragma unroll
            for (int i = 0; i < 8; ++i) {
                o8[i] = fbf(a[i]);
                s8[i] += a[i];
                q8[i] = fmaf(a[i], a[i], q8[i]);
            }
            up8[(size_t)o * 16 + c8] = o8;
        }
    }
    #pragma unroll
    for (int i = 0; i < 8; ++i) {
        sS[(rl * 16 + c8) * 8 + i] = s8[i];
        sQ[(rl * 16 + c8) * 8 + i] = q8[i];
    }
    __syncthreads();
    if (t < 128) {
        const int cc = t >> 3, ii = t & 7;
        float S = 0.f, Q = 0.f;
        #pragma unroll
        for (int r = 0; r < 16; ++r) {
            S += sS[(r * 16 + cc) * 8 + ii];
            Q += sQ[(r * 16 + cc) * 8 + ii];
        }
        parts[(size_t)b * 256 + t] = S;
        parts[(size_t)b * 256 + 128 + t] = Q;
    }
}

// =============== final: out = relu(bn2(h2)) + relu(bn0(up_raw)), fp32 out ===============
__global__ __launch_bounds__(256) void k_final(
    const us8* __restrict__ h2, const us8* __restrict__ upr, float* __restrict__ out,
    const float* __restrict__ stats2, const float* __restrict__ g2, const float* __restrict__ be2,
    const float* __restrict__ stats0, const float* __restrict__ g0, const float* __restrict__ b0)
{
    __shared__ float sc2[C], sh2[C], sc0[C], sh0[C];
    const int t = threadIdx.x;
    if (t < C) {
        float m2 = stats2[t] * (1.0f / NOUT);
        float v2 = stats2[C + t] * (1.0f / NOUT) - m2 * m2;
        float c2 = g2[t] * rsqrtf(v2 + EPSV);
        sc2[t] = c2; sh2[t] = fmaf(-m2, c2, be2[t]);
        float m0 = stats0[t] * (1.0f / NOUT);
        float v0 = stats0[C + t] * (1.0f / NOUT) - m0 * m0;
        float c0 = g0[t] * rsqrtf(v0 + EPSV);
        sc0[t] = c0; sh0[t] = fmaf(-m0, c0, b0[t]);
    }
    __syncthreads();
    const int idx0 = blockIdx.x * 256 + t;
    const int c8 = idx0 & 15;
    float l2s[8], l2h[8], l0s[8], l0h[8];
    #pragma unroll
    for (int i = 0; i < 8; ++i) {
        l2s[i] = sc2[c8 * 8 + i]; l2h[i] = sh2[c8 * 8 + i];
        l0s[i] = sc0[c8 * 8 + i]; l0h[i] = sh0[c8 * 8 + i];
    }
    const int total = NOUT * 16;
    for (int idx = idx0; idx < total; idx += gridDim.x * 256) {
        us8 h = h2[idx];
        us8 u = upr[idx];
        float o[8];
        #pragma unroll
        for (int i = 0; i < 8; ++i) {
            o[i] = fmaxf(fmaf(bff(h[i]), l2s[i], l2h[i]), 0.f)
                 + fmaxf(fmaf(bff(u[i]), l0s[i], l0h[i]), 0.f);
        }
        float4* dst = (float4*)&out[(size_t)idx * 8];
        dst[0] = make_float4(o[0], o[1], o[2], o[3]);
        dst[1] = make_float4(o[4], o[5], o[6], o[7]);
    }
}

extern "C" void kernel_launch(void* const* d_in, const int* in_sizes, int n_in,
                              void* d_out, int out_size, void* d_ws, size_t ws_size,
                              hipStream_t stream)
{
    const float* x    = (const float*)d_in[0];
    const float* skip = (const float*)d_in[1];
    const int*   pin  = (const int*)d_in[2];
    const int*   pout = (const int*)d_in[3];
    const float* Wup  = (const float*)d_in[4];
    const float* g0   = (const float*)d_in[5];
    const float* b0   = (const float*)d_in[6];
    const float* W1   = (const float*)d_in[7];
    const float* b1   = (const float*)d_in[8];
    const float* g1   = (const float*)d_in[9];
    const float* be1  = (const float*)d_in[10];
    const float* W2   = (const float*)d_in[11];
    const float* b2   = (const float*)d_in[12];
    const float* g2   = (const float*)d_in[13];
    const float* be2  = (const float*)d_in[14];
    float* outp = (float*)d_out;

    // ws layout: Y (82MB) reused by h1/h2 after sortgather; up_raw separate
    char* base = (char*)d_ws;
    unsigned short* Y      = (unsigned short*)base;               // 81,920,000 B
    unsigned short* h1     = (unsigned short*)base;               // alias (Y dead)
    unsigned short* h2     = (unsigned short*)(base + 40960000);  // alias (no overlap with h1)
    unsigned short* up_raw = (unsigned short*)(base + 81920000);  // 38,400,000 B
    char* p = base + 81920000 + 38400000;
    unsigned short* WT = (unsigned short*)p; p += (size_t)11 * 16384 * 2;
    unsigned int* bbuf = (unsigned int*)p;  p += (size_t)NSTR * NBUCK * SCAP * 4;   // 14.4 MB
    int* bcnt      = (int*)p; p += (size_t)NSTR * NBUCK * 4;
    float* parts0  = (float*)p; p += (size_t)NBUCK * 256 * 4;
    float* parts1  = (float*)p; p += (size_t)GM * 256 * 4;
    float* parts2  = (float*)p; p += (size_t)GM * 256 * 4;
    float* stats   = (float*)p; p += 3 * 256 * 4;   // stats0 | stats1 | stats2

    hipMemsetAsync(bcnt, 0, (size_t)NSTR * NBUCK * 4, stream);
    hipMemsetAsync(stats, 0, 3 * 256 * 4, stream);

    // 0. weights -> bf16 transposed
    k_prep_w<<<(11 * 16384 + 255) / 256, 256, 0, stream>>>(Wup, W1, W2, WT);

    // 1. Y[k] = x @ Wup[k]
    k_up<<<GUP, 256, 0, stream>>>(x, WT, Y);

    // 2. bucket append (LDS-aggregated, XCD-striped)
    k_bucket2<<<GBUCK, 256, 0, stream>>>(pout, pin, bcnt, bbuf);

    // 3. fused sort+gather -> up_raw bf16 + BN0 stats
    k_sortgather<<<NBUCK, 256, 0, stream>>>(bcnt, bbuf, (const us8*)Y, (us8*)up_raw, parts0);
    k_reduce<<<16, 256, 0, stream>>>(parts0, NBUCK, stats);

    // 4. h1 = bf16( relu(bn0(up_raw)) @ W1[:128] + skip @ W1[128:] + b1 ) + BN1 stats
    k_mfma<2, true, true><<<GM2, 512, 0, stream>>>(
        up_raw, skip, WT + (size_t)8 * 16384, b1, h1, NOUT, stats, g0, b0, parts1);
    k_reduce<<<16, 256, 0, stream>>>(parts1, GM2, stats + 256);

    // 5. h2 = bf16( relu(bn1(h1)) @ W2 + b2 ) + BN2 stats
    k_mfma<1, true, true><<<GM2, 512, 0, stream>>>(
        h1, nullptr, WT + (size_t)10 * 16384, b2, h2, NOUT, stats + 256, g1, be1, parts2);
    k_reduce<<<16, 256, 0, stream>>>(parts2, GM2, stats + 512);

    // 6. out = relu(bn2(h2)) + relu(bn0(up_raw))
    k_final<<<1024, 256, 0, stream>>>((const us8*)h2, (const us8*)up_raw, outp,
        stats + 512, g2, be2, stats, g0, b0);
}